// Round 7
// baseline (487.835 us; speedup 1.0000x reference)
//
#include <hip/hip_runtime.h>
#include <math.h>

#define BATCH 8
#define NPTS 2048
#define MPTS 2048
#define TPB 512                       // 8 waves
#define RPB 16                        // rows per block
#define KC 4                          // columns per thread: 2048/512
#define RPR 4                         // rows per round
#define NRND (RPB/RPR)                // 4 rounds
#define CHUNKS (NPTS/RPB)             // 128
#define NBLK (BATCH*CHUNKS)           // 1024

// Persistent state (re-initialized every kernel_launch -> deterministic).
// Buffer rotation removes the separate k_cols kernel:
//   level l reads colsum from g_cbuf[l%3], accumulates next level's colsum
//   into g_cbuf[(l+1)%3], zeroes g_cbuf[(l+2)%3] (nobody reads it this level).
//   remainr ping-pongs g_rbuf[l&1] -> g_rbuf[(l+1)&1] (writes idempotent
//   across the 128 blocks of a batch -> deterministic).
__device__ float g_remainl[BATCH*NPTS];
__device__ float g_s[BATCH*NPTS];
__device__ float g_rbuf[2][BATCH*MPTS];
__device__ float g_cbuf[3][BATCH*MPTS];
__device__ float g_cost;

#if __has_builtin(__builtin_amdgcn_exp2f)
#define EXP2(x) __builtin_amdgcn_exp2f(x)
#else
#define EXP2(x) exp2f(x)
#endif
#if __has_builtin(__builtin_amdgcn_sqrtf)
#define FSQRT(x) __builtin_amdgcn_sqrtf(x)
#else
#define FSQRT(x) sqrtf(x)
#endif
#if __has_builtin(__builtin_amdgcn_rcpf)
#define RCP(x) __builtin_amdgcn_rcpf(x)
#else
#define RCP(x) (1.0f/(x))
#endif

#define D2(rd, k) fmaf(rd.x, cx[k], fmaf(rd.y, cy[k],                      \
                   fmaf(rd.z, cz[k], rd.w + rc2[k])))

__global__ __launch_bounds__(256) void k_init() {
  const int i = blockIdx.x*256 + threadIdx.x;   // 64 x 256 = 16384
  g_cbuf[0][i] = 0.f;     // k_a0 accumulates level-0 colsum here
  g_cbuf[1][i] = 0.f;     // k_ca(0) accumulates level-1 colsum here
  g_rbuf[0][i] = 1.f;     // initial remainr (factorr = 1)
  if (i == 0) g_cost = 0.f;
}

// A-part of level 0 (remainl = remainr = 1): computes s(0), colsum(0).
__global__ __launch_bounds__(TPB) void k_a0(const float* __restrict__ gen,
                                            const float* __restrict__ gt,
                                            float c1) {
  const int blk = blockIdx.x, b = blk >> 7, chunk = blk & (CHUNKS-1);
  const int t = threadIdx.x, wave = t >> 6, lane = t & 63;
  const int rowbase = b*NPTS + chunk*RPB;
  __shared__ float4 rowdat[RPB];
  __shared__ float4 red[2][8];       // [buf][wave] : s1 of 4 rows
  __shared__ float4 scn_sh[2];
  float cx[KC], cy[KC], cz[KC], rc2[KC];
  #pragma unroll
  for (int k = 0; k < KC; ++k) {
    const int gi = (b*MPTS + t + TPB*k)*3;
    cx[k] = gt[gi]; cy[k] = gt[gi+1]; cz[k] = gt[gi+2];
    rc2[k] = cx[k]*cx[k] + cy[k]*cy[k] + cz[k]*cz[k];
  }
  if (t < RPB) {
    const int gi = (rowbase + t)*3;
    const float px = gen[gi], py = gen[gi+1], pz = gen[gi+2];
    rowdat[t] = make_float4(-2.f*px, -2.f*py, -2.f*pz, px*px+py*py+pz*pz);
    g_remainl[rowbase + t] = 1.0f;
  }
  __syncthreads();
  float colacc[KC] = {0.f, 0.f, 0.f, 0.f};
  #pragma unroll 1
  for (int rr = 0; rr < NRND; ++rr) {
    const int buf = rr & 1;
    float w[RPR][KC], s1[RPR];
    #pragma unroll
    for (int j = 0; j < RPR; ++j) {
      const float4 rd = rowdat[RPR*rr + j];
      float a1 = 0.f;
      #pragma unroll
      for (int k = 0; k < KC; ++k) {
        const float e = EXP2(c1*D2(rd, k));
        w[j][k] = e; a1 += e;
      }
      s1[j] = a1;
    }
    #pragma unroll
    for (int off = 1; off < 64; off <<= 1) {
      #pragma unroll
      for (int j = 0; j < RPR; ++j) s1[j] += __shfl_xor(s1[j], off);
    }
    if (lane == 0) red[buf][wave] = make_float4(s1[0], s1[1], s1[2], s1[3]);
    __syncthreads();
    if (wave < RPR) {                 // distributed mid: wave j -> row j
      float s1t = 0.f;
      if (lane < 8) {
        const float4 v = red[buf][lane];
        s1t = (wave == 0) ? v.x : (wave == 1) ? v.y : (wave == 2) ? v.z : v.w;
      }
      #pragma unroll
      for (int off = 1; off < 8; off <<= 1) s1t += __shfl_xor(s1t, off);
      const float scn = RCP(s1t + 1e-9f);   // remainl = 1
      if (lane == 0) {
        ((float*)&scn_sh[buf])[wave] = scn;
        g_s[rowbase + RPR*rr + wave] = scn;
      }
    }
    __syncthreads();
    const float4 sv = scn_sh[buf];
    #pragma unroll
    for (int k = 0; k < KC; ++k)
      colacc[k] = fmaf(w[0][k], sv.x, fmaf(w[1][k], sv.y,
                  fmaf(w[2][k], sv.z, fmaf(w[3][k], sv.w, colacc[k]))));
  }
  #pragma unroll
  for (int k = 0; k < KC; ++k)
    atomicAdd(&g_cbuf[0][b*MPTS + t + TPB*k], colacc[k]);   // rr == 1
}

// Fused [fold of k_cols(l)] + C(level l) + A(level l+1).
// eq = exp2(cq*d2) is next level's exp; e1 = (eq^2)^2 (c1 = 4*cq exactly).
// LAST (l==8): next level coeff is 0 -> eq = 1.
template<bool LAST>
__global__ __launch_bounds__(TPB) void k_ca(const float* __restrict__ gen,
                                            const float* __restrict__ gt,
                                            float c1, float cq, int l) {
  const int blk = blockIdx.x, b = blk >> 7, chunk = blk & (CHUNKS-1);
  const int t = threadIdx.x, wave = t >> 6, lane = t & 63;
  const int rowbase = b*NPTS + chunk*RPB;
  const float* __restrict__ cs_in = g_cbuf[l % 3];
  float* __restrict__ cs_out  = g_cbuf[(l+1) % 3];
  float* __restrict__ cs_zero = g_cbuf[(l+2) % 3];
  const float* __restrict__ rr_in = g_rbuf[l & 1];
  float* __restrict__ rr_out = g_rbuf[(l+1) & 1];
  __shared__ float4 rowdat[RPB];
  __shared__ float  sc_s[RPB], rl_s[RPB];
  __shared__ float4 red[2][2][8];    // [buf][rowpair][wave] : (s1,rs) x2 rows
  __shared__ float4 scn_sh[2];
  __shared__ float  cred[8];
  // column stage + folded k_cols
  float cx[KC], cy[KC], cz[KC], rc2[KC], pp[KC], rrn[KC];
  #pragma unroll
  for (int k = 0; k < KC; ++k) {
    const int m = b*MPTS + t + TPB*k;
    const int gi = m*3;
    cx[k] = gt[gi]; cy[k] = gt[gi+1]; cz[k] = gt[gi+2];
    rc2[k] = cx[k]*cx[k] + cy[k]*cy[k] + cz[k]*cz[k];
    const float cs = cs_in[m], rrv = rr_in[m];
    const float ratio = fminf(rrv / (cs + 1e-9f), 1.0f);
    pp[k]  = rrv*ratio;
    rrn[k] = fmaxf(rrv - cs*ratio, 0.0f);
    rr_out[m] = rrn[k];              // idempotent across blocks
    cs_zero[m] = 0.0f;               // pre-zero for level l+2
  }
  if (t < RPB) {
    const int gi = (rowbase + t)*3;
    const float px = gen[gi], py = gen[gi+1], pz = gen[gi+2];
    rowdat[t] = make_float4(-2.f*px, -2.f*py, -2.f*pz, px*px+py*py+pz*pz);
    sc_s[t] = g_s[rowbase + t];
    rl_s[t] = g_remainl[rowbase + t];
  }
  __syncthreads();
  float colacc[KC] = {0.f, 0.f, 0.f, 0.f};
  float costacc = 0.f;
  #pragma unroll 1
  for (int rr = 0; rr < NRND; ++rr) {
    const int buf = rr & 1;
    float w[RPR][KC], s1[RPR], rs[RPR];
    #pragma unroll
    for (int j = 0; j < RPR; ++j) {
      const float4 rd = rowdat[RPR*rr + j];
      float a1 = 0.f, a2 = 0.f, ar = 0.f;
      #pragma unroll
      for (int k = 0; k < KC; ++k) {
        const float d2 = D2(rd, k);
        float e1, wq;
        if (LAST) { e1 = EXP2(c1*d2); wq = rrn[k]; }
        else { const float eq = EXP2(cq*d2); const float e2 = eq*eq;
               e1 = e2*e2; wq = eq*rrn[k]; }
        w[j][k] = wq; ar += wq;
        const float u = e1*pp[k];
        a1 += u;
        a2 = fmaf(u, FSQRT(fmaxf(d2, 1e-20f)), a2);
      }
      s1[j] = a1; rs[j] = ar;
      costacc = fmaf(sc_s[RPR*rr + j], a2, costacc);
    }
    #pragma unroll
    for (int off = 1; off < 64; off <<= 1) {
      #pragma unroll
      for (int j = 0; j < RPR; ++j) {
        s1[j] += __shfl_xor(s1[j], off);
        rs[j] += __shfl_xor(rs[j], off);
      }
    }
    if (lane == 0) {
      red[buf][0][wave] = make_float4(s1[0], rs[0], s1[1], rs[1]);
      red[buf][1][wave] = make_float4(s1[2], rs[2], s1[3], rs[3]);
    }
    __syncthreads();
    if (wave < RPR) {                 // distributed mid: wave j -> row j
      const int r = RPR*rr + wave;
      float s1t = 0.f, rst = 0.f;
      if (lane < 8) {
        const float4 v = red[buf][wave >> 1][lane];
        if (wave & 1) { s1t = v.z; rst = v.w; }
        else          { s1t = v.x; rst = v.y; }
      }
      #pragma unroll
      for (int off = 1; off < 8; off <<= 1) {
        s1t += __shfl_xor(s1t, off);
        rst += __shfl_xor(rst, off);
      }
      const float rl_new = fmaxf(rl_s[r] - sc_s[r]*s1t, 0.0f);
      const float scn = rl_new * RCP(rst + 1e-9f);
      if (lane == 0) {
        ((float*)&scn_sh[buf])[wave] = scn;
        g_remainl[rowbase + r] = rl_new;
        g_s[rowbase + r] = scn;
      }
    }
    __syncthreads();
    const float4 sv = scn_sh[buf];
    #pragma unroll
    for (int k = 0; k < KC; ++k)
      colacc[k] = fmaf(w[0][k], sv.x, fmaf(w[1][k], sv.y,
                  fmaf(w[2][k], sv.z, fmaf(w[3][k], sv.w, colacc[k]))));
  }
  #pragma unroll
  for (int k = 0; k < KC; ++k)
    atomicAdd(&cs_out[b*MPTS + t + TPB*k], colacc[k]);
  #pragma unroll
  for (int off = 1; off < 64; off <<= 1) costacc += __shfl_xor(costacc, off);
  if (lane == 0) cred[wave] = costacc;
  __syncthreads();
  if (t == 0) {
    float c = 0.f;
    #pragma unroll
    for (int ww = 0; ww < 8; ++ww) c += cred[ww];
    atomicAdd(&g_cost, c);
  }
}

// C-part of level 9 (coeff 0 -> weight = p): cost only, barrier-free loop.
// Reads colsum from cbuf[9%3=0], remainr from rbuf[9&1=1].
__global__ __launch_bounds__(TPB) void k_c_last(const float* __restrict__ gen,
                                                const float* __restrict__ gt) {
  const int blk = blockIdx.x, b = blk >> 7, chunk = blk & (CHUNKS-1);
  const int t = threadIdx.x, wave = t >> 6, lane = t & 63;
  const int rowbase = b*NPTS + chunk*RPB;
  const float* __restrict__ cs_in = g_cbuf[0];
  const float* __restrict__ rr_in = g_rbuf[1];
  __shared__ float4 rowdat[RPB];
  __shared__ float  sc_s[RPB];
  __shared__ float  cred[8];
  float cx[KC], cy[KC], cz[KC], rc2[KC], pp[KC];
  #pragma unroll
  for (int k = 0; k < KC; ++k) {
    const int m = b*MPTS + t + TPB*k;
    const int gi = m*3;
    cx[k] = gt[gi]; cy[k] = gt[gi+1]; cz[k] = gt[gi+2];
    rc2[k] = cx[k]*cx[k] + cy[k]*cy[k] + cz[k]*cz[k];
    const float cs = cs_in[m], rrv = rr_in[m];
    const float ratio = fminf(rrv / (cs + 1e-9f), 1.0f);
    pp[k] = rrv*ratio;
  }
  if (t < RPB) {
    const int gi = (rowbase + t)*3;
    const float px = gen[gi], py = gen[gi+1], pz = gen[gi+2];
    rowdat[t] = make_float4(-2.f*px, -2.f*py, -2.f*pz, px*px+py*py+pz*pz);
    sc_s[t] = g_s[rowbase + t];
  }
  __syncthreads();
  float costacc = 0.f;
  #pragma unroll 1
  for (int r = 0; r < RPB; ++r) {
    const float4 rd = rowdat[r];
    float s2 = 0.f;
    #pragma unroll
    for (int k = 0; k < KC; ++k)
      s2 = fmaf(pp[k], FSQRT(fmaxf(D2(rd, k), 1e-20f)), s2);
    costacc = fmaf(sc_s[r], s2, costacc);
  }
  #pragma unroll
  for (int off = 1; off < 64; off <<= 1) costacc += __shfl_xor(costacc, off);
  if (lane == 0) cred[wave] = costacc;
  __syncthreads();
  if (t == 0) {
    float c = 0.f;
    #pragma unroll
    for (int ww = 0; ww < 8; ++ww) c += cred[ww];
    atomicAdd(&g_cost, c);
  }
}

__global__ void k_final(float* __restrict__ out) {
  out[0] = g_cost * (1.0f / (float)(BATCH*NPTS));
}

extern "C" void kernel_launch(void* const* d_in, const int* in_sizes, int n_in,
                              void* d_out, int out_size, void* d_ws, size_t ws_size,
                              hipStream_t stream) {
  const float* gen = (const float*)d_in[0];   // pc_gen [8,2048,3] f32
  const float* gt  = (const float*)d_in[1];   // pc_gt  [8,2048,3] f32
  float* out = (float*)d_out;

  const double L[10] = {-16384.0, -4096.0, -1024.0, -256.0, -64.0,
                        -16.0, -4.0, -1.0, -0.25, 0.0};
  float c[10];
  for (int i = 0; i < 10; ++i) c[i] = (float)(L[i] * 1.4426950408889634);

  k_init<<<64, 256, 0, stream>>>();
  k_a0<<<NBLK, TPB, 0, stream>>>(gen, gt, c[0]);
  for (int l = 0; l < 8; ++l)
    k_ca<false><<<NBLK, TPB, 0, stream>>>(gen, gt, c[l], c[l+1], l);
  k_ca<true><<<NBLK, TPB, 0, stream>>>(gen, gt, c[8], 0.f, 8);
  k_c_last<<<NBLK, TPB, 0, stream>>>(gen, gt);
  k_final<<<1, 1, 0, stream>>>(out);
}

// Round 8
// 366.693 us; speedup vs baseline: 1.3304x; 1.3304x over previous
//
#include <hip/hip_runtime.h>
#include <math.h>

#define BATCH 8
#define NPTS 2048
#define MPTS 2048
#define TPB 256                       // 4 waves
#define RPB 16                        // rows per block
#define KC 8                          // columns per thread: 2048/256
#define RPR 2                         // rows per round
#define NRND (RPB/RPR)                // 8 rounds
#define CHUNKS (NPTS/RPB)             // 128
#define NBLK (BATCH*CHUNKS)           // 1024

// Persistent state (re-initialized every kernel_launch -> deterministic).
// colsum rotation: level l reads g_cbuf[l%3], accumulates into g_cbuf[(l+1)%3],
// zeroes g_cbuf[(l+2)%3]. remainr ping-pongs g_rbuf[l&1] -> g_rbuf[(l+1)&1].
// rr/zero writes are gated to the chunk==0 block of each batch (values are
// identical across blocks; kernel-boundary ordering makes this safe).
__device__ float g_remainl[BATCH*NPTS];
__device__ float g_s[BATCH*NPTS];
__device__ float g_rbuf[2][BATCH*MPTS];
__device__ float g_cbuf[3][BATCH*MPTS];
__device__ float g_cost;

#if __has_builtin(__builtin_amdgcn_exp2f)
#define EXP2(x) __builtin_amdgcn_exp2f(x)
#else
#define EXP2(x) exp2f(x)
#endif
#if __has_builtin(__builtin_amdgcn_sqrtf)
#define FSQRT(x) __builtin_amdgcn_sqrtf(x)
#else
#define FSQRT(x) sqrtf(x)
#endif
#if __has_builtin(__builtin_amdgcn_rcpf)
#define RCP(x) __builtin_amdgcn_rcpf(x)
#else
#define RCP(x) (1.0f/(x))
#endif

#define D2(rd, k) fmaf(rd.x, cx[k], fmaf(rd.y, cy[k],                      \
                   fmaf(rd.z, cz[k], rd.w + rc2[k])))

__global__ __launch_bounds__(256) void k_init() {
  const int i = blockIdx.x*256 + threadIdx.x;   // 64 x 256 = 16384
  g_cbuf[0][i] = 0.f;     // k_a0 output
  g_cbuf[1][i] = 0.f;     // k_ca(0) output
  g_rbuf[0][i] = 1.f;     // initial remainr (factorr = 1)
  if (i == 0) g_cost = 0.f;
}

// A-part of level 0 (remainl = remainr = 1): computes s(0), colsum(0).
__global__ __launch_bounds__(TPB) void k_a0(const float* __restrict__ gen,
                                            const float* __restrict__ gt,
                                            float c1) {
  const int blk = blockIdx.x, b = blk >> 7, chunk = blk & (CHUNKS-1);
  const int t = threadIdx.x, wave = t >> 6, lane = t & 63;
  const int rowbase = b*NPTS + chunk*RPB;
  __shared__ float4 rowdat[RPB];
  __shared__ float2 red[2][4];       // [buf][wave] : (s1 row0, s1 row1)
  __shared__ float  cred[4];
  float cx[KC], cy[KC], cz[KC], rc2[KC];
  #pragma unroll
  for (int k = 0; k < KC; ++k) {
    const int gi = (b*MPTS + t + TPB*k)*3;
    cx[k] = gt[gi]; cy[k] = gt[gi+1]; cz[k] = gt[gi+2];
    rc2[k] = cx[k]*cx[k] + cy[k]*cy[k] + cz[k]*cz[k];
  }
  if (t < RPB) {
    const int gi = (rowbase + t)*3;
    const float px = gen[gi], py = gen[gi+1], pz = gen[gi+2];
    rowdat[t] = make_float4(-2.f*px, -2.f*py, -2.f*pz, px*px+py*py+pz*pz);
    g_remainl[rowbase + t] = 1.0f;
  }
  __syncthreads();
  float colacc[KC];
  #pragma unroll
  for (int k = 0; k < KC; ++k) colacc[k] = 0.f;
  #pragma unroll 1
  for (int rr = 0; rr < NRND; ++rr) {
    const int buf = rr & 1;
    const float4 rd0 = rowdat[RPR*rr+0];
    const float4 rd1 = rowdat[RPR*rr+1];
    float w0[KC], w1[KC];
    float s1a = 0.f, s1b = 0.f;
    #pragma unroll
    for (int k = 0; k < KC; ++k) {
      const float ea = EXP2(c1*D2(rd0, k));
      const float eb = EXP2(c1*D2(rd1, k));
      w0[k] = ea; s1a += ea;
      w1[k] = eb; s1b += eb;
    }
    #pragma unroll
    for (int off = 1; off < 64; off <<= 1) {
      s1a += __shfl_xor(s1a, off);
      s1b += __shfl_xor(s1b, off);
    }
    if (lane == 0) red[buf][wave] = make_float2(s1a, s1b);
    __syncthreads();
    // every wave redundantly reduces the 4 partials (broadcast LDS reads)
    const float2 v0 = red[buf][0], v1 = red[buf][1];
    const float2 v2 = red[buf][2], v3 = red[buf][3];
    const float scn0 = RCP(v0.x+v1.x+v2.x+v3.x + 1e-9f);   // remainl = 1
    const float scn1 = RCP(v0.y+v1.y+v2.y+v3.y + 1e-9f);
    if (t == 0) {
      g_s[rowbase + RPR*rr + 0] = scn0;
      g_s[rowbase + RPR*rr + 1] = scn1;
    }
    #pragma unroll
    for (int k = 0; k < KC; ++k)
      colacc[k] = fmaf(w0[k], scn0, fmaf(w1[k], scn1, colacc[k]));
  }
  #pragma unroll
  for (int k = 0; k < KC; ++k)
    atomicAdd(&g_cbuf[0][b*MPTS + t + TPB*k], colacc[k]);   // rr == 1
  (void)cred;
}

// Fused [k_cols(l)] + C(level l) + A(level l+1).
// eq = exp2(cq*d2) is next level's exp; e1 = (eq^2)^2 (c1 = 4*cq exactly).
// LAST (l==8): next level coeff is 0 -> eq = 1.
template<bool LAST>
__global__ __launch_bounds__(TPB) void k_ca(const float* __restrict__ gen,
                                            const float* __restrict__ gt,
                                            float c1, float cq, int l) {
  const int blk = blockIdx.x, b = blk >> 7, chunk = blk & (CHUNKS-1);
  const int t = threadIdx.x, wave = t >> 6, lane = t & 63;
  const int rowbase = b*NPTS + chunk*RPB;
  const float* __restrict__ cs_in = g_cbuf[l % 3];
  float* __restrict__ cs_out  = g_cbuf[(l+1) % 3];
  float* __restrict__ cs_zero = g_cbuf[(l+2) % 3];
  const float* __restrict__ rr_in = g_rbuf[l & 1];
  float* __restrict__ rr_out = g_rbuf[(l+1) & 1];
  __shared__ float4 rowdat[RPB];
  __shared__ float  sc_s[RPB], rl_s[RPB];
  __shared__ float4 red[2][4];       // [buf][wave] : (s1_0, rs_0, s1_1, rs_1)
  __shared__ float  cred[4];
  // column stage + folded k_cols (global writes gated to chunk==0)
  float cx[KC], cy[KC], cz[KC], rc2[KC], pp[KC], rrn[KC];
  #pragma unroll
  for (int k = 0; k < KC; ++k) {
    const int m = b*MPTS + t + TPB*k;
    const int gi = m*3;
    cx[k] = gt[gi]; cy[k] = gt[gi+1]; cz[k] = gt[gi+2];
    rc2[k] = cx[k]*cx[k] + cy[k]*cy[k] + cz[k]*cz[k];
    const float cs = cs_in[m], rrv = rr_in[m];
    const float ratio = fminf(rrv / (cs + 1e-9f), 1.0f);
    pp[k]  = rrv*ratio;
    rrn[k] = fmaxf(rrv - cs*ratio, 0.0f);
    if (chunk == 0) { rr_out[m] = rrn[k]; cs_zero[m] = 0.0f; }
  }
  if (t < RPB) {
    const int gi = (rowbase + t)*3;
    const float px = gen[gi], py = gen[gi+1], pz = gen[gi+2];
    rowdat[t] = make_float4(-2.f*px, -2.f*py, -2.f*pz, px*px+py*py+pz*pz);
    sc_s[t] = g_s[rowbase + t];
    rl_s[t] = g_remainl[rowbase + t];
  }
  __syncthreads();
  float colacc[KC];
  #pragma unroll
  for (int k = 0; k < KC; ++k) colacc[k] = 0.f;
  float costacc = 0.f;
  #pragma unroll 1
  for (int rr = 0; rr < NRND; ++rr) {
    const int buf = rr & 1;
    const int r0 = RPR*rr, r1 = r0 + 1;
    const float4 rd0 = rowdat[r0];
    const float4 rd1 = rowdat[r1];
    float w0[KC], w1[KC];
    float s1a = 0.f, rsa = 0.f, s2a = 0.f;
    float s1b = 0.f, rsb = 0.f, s2b = 0.f;
    #pragma unroll
    for (int k = 0; k < KC; ++k) {
      {
        const float d2 = D2(rd0, k);
        float e1, wq;
        if (LAST) { e1 = EXP2(c1*d2); wq = rrn[k]; }
        else { const float eq = EXP2(cq*d2); const float e2 = eq*eq;
               e1 = e2*e2; wq = eq*rrn[k]; }
        w0[k] = wq; rsa += wq;
        const float u = e1*pp[k];
        s1a += u;
        s2a = fmaf(u, FSQRT(fmaxf(d2, 1e-20f)), s2a);
      }
      {
        const float d2 = D2(rd1, k);
        float e1, wq;
        if (LAST) { e1 = EXP2(c1*d2); wq = rrn[k]; }
        else { const float eq = EXP2(cq*d2); const float e2 = eq*eq;
               e1 = e2*e2; wq = eq*rrn[k]; }
        w1[k] = wq; rsb += wq;
        const float u = e1*pp[k];
        s1b += u;
        s2b = fmaf(u, FSQRT(fmaxf(d2, 1e-20f)), s2b);
      }
    }
    costacc = fmaf(sc_s[r0], s2a, costacc);
    costacc = fmaf(sc_s[r1], s2b, costacc);
    #pragma unroll
    for (int off = 1; off < 64; off <<= 1) {
      s1a += __shfl_xor(s1a, off); rsa += __shfl_xor(rsa, off);
      s1b += __shfl_xor(s1b, off); rsb += __shfl_xor(rsb, off);
    }
    if (lane == 0) red[buf][wave] = make_float4(s1a, rsa, s1b, rsb);
    __syncthreads();
    // every wave redundantly reduces the 4 partials (broadcast LDS reads)
    const float4 v0 = red[buf][0], v1 = red[buf][1];
    const float4 v2 = red[buf][2], v3 = red[buf][3];
    const float s1t0 = v0.x+v1.x+v2.x+v3.x;
    const float rst0 = v0.y+v1.y+v2.y+v3.y;
    const float s1t1 = v0.z+v1.z+v2.z+v3.z;
    const float rst1 = v0.w+v1.w+v2.w+v3.w;
    const float rl0 = fmaxf(rl_s[r0] - sc_s[r0]*s1t0, 0.0f);
    const float rl1 = fmaxf(rl_s[r1] - sc_s[r1]*s1t1, 0.0f);
    const float scn0 = rl0 * RCP(rst0 + 1e-9f);
    const float scn1 = rl1 * RCP(rst1 + 1e-9f);
    if (t == 0) {
      g_remainl[rowbase + r0] = rl0;
      g_remainl[rowbase + r1] = rl1;
      g_s[rowbase + r0] = scn0;
      g_s[rowbase + r1] = scn1;
    }
    #pragma unroll
    for (int k = 0; k < KC; ++k)
      colacc[k] = fmaf(w0[k], scn0, fmaf(w1[k], scn1, colacc[k]));
  }
  #pragma unroll
  for (int k = 0; k < KC; ++k)
    atomicAdd(&cs_out[b*MPTS + t + TPB*k], colacc[k]);
  #pragma unroll
  for (int off = 1; off < 64; off <<= 1) costacc += __shfl_xor(costacc, off);
  if (lane == 0) cred[wave] = costacc;
  __syncthreads();
  if (t == 0)
    atomicAdd(&g_cost, cred[0] + cred[1] + cred[2] + cred[3]);
}

// C-part of level 9 (coeff 0 -> weight = p): cost only, barrier-free loop.
// Reads colsum from cbuf[9%3=0], remainr from rbuf[9&1=1].
__global__ __launch_bounds__(TPB) void k_c_last(const float* __restrict__ gen,
                                                const float* __restrict__ gt) {
  const int blk = blockIdx.x, b = blk >> 7, chunk = blk & (CHUNKS-1);
  const int t = threadIdx.x, wave = t >> 6, lane = t & 63;
  const int rowbase = b*NPTS + chunk*RPB;
  const float* __restrict__ cs_in = g_cbuf[0];
  const float* __restrict__ rr_in = g_rbuf[1];
  __shared__ float4 rowdat[RPB];
  __shared__ float  sc_s[RPB];
  __shared__ float  cred[4];
  float cx[KC], cy[KC], cz[KC], rc2[KC], pp[KC];
  #pragma unroll
  for (int k = 0; k < KC; ++k) {
    const int m = b*MPTS + t + TPB*k;
    const int gi = m*3;
    cx[k] = gt[gi]; cy[k] = gt[gi+1]; cz[k] = gt[gi+2];
    rc2[k] = cx[k]*cx[k] + cy[k]*cy[k] + cz[k]*cz[k];
    const float cs = cs_in[m], rrv = rr_in[m];
    const float ratio = fminf(rrv / (cs + 1e-9f), 1.0f);
    pp[k] = rrv*ratio;
  }
  if (t < RPB) {
    const int gi = (rowbase + t)*3;
    const float px = gen[gi], py = gen[gi+1], pz = gen[gi+2];
    rowdat[t] = make_float4(-2.f*px, -2.f*py, -2.f*pz, px*px+py*py+pz*pz);
    sc_s[t] = g_s[rowbase + t];
  }
  __syncthreads();
  float costacc = 0.f;
  #pragma unroll 1
  for (int r = 0; r < RPB; ++r) {
    const float4 rd = rowdat[r];
    float s2 = 0.f;
    #pragma unroll
    for (int k = 0; k < KC; ++k)
      s2 = fmaf(pp[k], FSQRT(fmaxf(D2(rd, k), 1e-20f)), s2);
    costacc = fmaf(sc_s[r], s2, costacc);
  }
  #pragma unroll
  for (int off = 1; off < 64; off <<= 1) costacc += __shfl_xor(costacc, off);
  if (lane == 0) cred[wave] = costacc;
  __syncthreads();
  if (t == 0)
    atomicAdd(&g_cost, cred[0] + cred[1] + cred[2] + cred[3]);
}

__global__ void k_final(float* __restrict__ out) {
  out[0] = g_cost * (1.0f / (float)(BATCH*NPTS));
}

extern "C" void kernel_launch(void* const* d_in, const int* in_sizes, int n_in,
                              void* d_out, int out_size, void* d_ws, size_t ws_size,
                              hipStream_t stream) {
  const float* gen = (const float*)d_in[0];   // pc_gen [8,2048,3] f32
  const float* gt  = (const float*)d_in[1];   // pc_gt  [8,2048,3] f32
  float* out = (float*)d_out;

  const double L[10] = {-16384.0, -4096.0, -1024.0, -256.0, -64.0,
                        -16.0, -4.0, -1.0, -0.25, 0.0};
  float c[10];
  for (int i = 0; i < 10; ++i) c[i] = (float)(L[i] * 1.4426950408889634);

  k_init<<<64, 256, 0, stream>>>();
  k_a0<<<NBLK, TPB, 0, stream>>>(gen, gt, c[0]);
  for (int l = 0; l < 8; ++l)
    k_ca<false><<<NBLK, TPB, 0, stream>>>(gen, gt, c[l], c[l+1], l);
  k_ca<true><<<NBLK, TPB, 0, stream>>>(gen, gt, c[8], 0.f, 8);
  k_c_last<<<NBLK, TPB, 0, stream>>>(gen, gt);
  k_final<<<1, 1, 0, stream>>>(out);
}